// Round 8
// baseline (91.439 us; speedup 1.0000x reference)
//
#include <hip/hip_runtime.h>

// QSP via Laurent polynomial, one kernel (R18).
// R13-R17 measured: dur is flat (~90) across kernel micro-variants and
// tracks TOTAL issued work, not profiled kernel time -> cut FLOPs.
// R18: pair t and 127-t. With m = 127-2t:
//   u00 = sum_{k=0}^{63} P_k cos((2k+1)theta) + Q_k sin((2k+1)theta),
//   P_k = gamma_{63-k} + gamma_{64+k},  Q_k = i(gamma_{64+k} - gamma_{63-k}).
// Coupled 3-term recurrences (K = 2cos2theta): c' = K c - c_prev, s' = K s
// - s_prev; seeds c_{-1}=cos, s_{-1}=-sin give c1=cos3t, s1=sin3t (exact).
// Per elem: 64*(4 accum + 2 advance) = 384 FMA vs Horner's 512 (-25%),
// the e^{-127 i theta} rotation + its sincos are absorbed, and only ONE
// sincos per element (K = 2 - 4 sin^2). Gamma recurrence unchanged
// (designated wave blockIdx&3, LDS handoff as float2[128]).

__device__ __forceinline__ float wave_shr1(float x) {
    // lane L <- lane L-1, lane 0 <- 0 (DPP wave_shr:1, bound_ctrl=1)
    return __builtin_bit_cast(float,
        __builtin_amdgcn_update_dpp(0, __builtin_bit_cast(int, x),
                                    0x138, 0xf, 0xf, true));
}

__device__ __forceinline__ float rlane(float x, int l) {
    // broadcast lane l's value to all lanes (l must be wave-uniform)
    return __builtin_bit_cast(float,
        __builtin_amdgcn_readlane(__builtin_bit_cast(int, x), l));
}

__global__ __launch_bounds__(256, 4) void qsp_fused(
    const float* __restrict__ th,
    const float* __restrict__ phis,
    float* __restrict__ out,    // [0,B): real, [B,2B): imag
    int Bq8)                     // B/8
{
    __shared__ float2 gsh2[128];   // gamma_t, t = 0..127

    const int tid  = threadIdx.x;
    const int lane = tid & 63;
    const int wv   = tid >> 6;
    const int gwv  = blockIdx.x & 3;   // designated gamma wave for this block
    const int idx  = blockIdx.x * blockDim.x + tid;
    const int lidx = (idx < Bq8) ? idx : 0;

    // issue theta loads first; latency hides under gamma/prologue
    const float4 ta = ((const float4*)th)[2 * lidx];
    const float4 tb = ((const float4*)th)[2 * lidx + 1];

    if (wv == gwv) {
        // ---- gamma recurrence (validated R6-R17), this wave only -----------
        float sp, cp;
        __sincosf(phis[lane], &sp, &cp);
        const float hAx = 0.5f * cp, hAy = 0.5f * sp;        // k = lane
        __sincosf(phis[lane + 64], &sp, &cp);
        const float hBx = 0.5f * cp, hBy = 0.5f * sp;        // k = lane + 64

        float A0r = 0.f, A0i = 0.f, B0r = 0.f, B0i = 0.f;
        float A1r = 0.f, A1i = 0.f, B1r = 0.f, B1i = 0.f;
        const float h0x = rlane(hAx, 0), h0y = rlane(hAy, 0);
        if (lane == 0) { A0r = 2.f * h0x; A0i = 2.f * h0y; } // A[0] = e_0

        #define QSP_REC(hx_, hy_)                                             \
        {                                                                     \
            const float hx = (hx_), hy = (hy_);                               \
            const float pAr = wave_shr1(A1r), pAi = wave_shr1(A1i);           \
            const float pBr = wave_shr1(B1r), pBi = wave_shr1(B1i);           \
            const float u0r = pAr + pBr, u0i = pAi + pBi;                     \
            const float v0r = A0r - B0r, v0i = A0i - B0i;                     \
            const float sA0r = u0r + v0r, sA0i = u0i + v0i;                   \
            const float sB0r = u0r - v0r, sB0i = u0i - v0i;                   \
            const float u1r = A0r + B0r, u1i = A0i + B0i;                     \
            const float v1r = A1r - B1r, v1i = A1i - B1i;                     \
            const float sA1r = u1r + v1r, sA1i = u1i + v1i;                   \
            const float sB1r = u1r - v1r, sB1i = u1i - v1i;                   \
            A0r = fmaf(hx, sA0r, -hy * sA0i);                                 \
            A0i = fmaf(hx, sA0i,  hy * sA0r);                                 \
            B0r = fmaf(hx, sB0r,  hy * sB0i);                                 \
            B0i = fmaf(hx, sB0i, -hy * sB0r);                                 \
            A1r = fmaf(hx, sA1r, -hy * sA1i);                                 \
            A1i = fmaf(hx, sA1i,  hy * sA1r);                                 \
            B1r = fmaf(hx, sB1r,  hy * sB1i);                                 \
            B1i = fmaf(hx, sB1i, -hy * sB1r);                                 \
        }
        #pragma unroll 4
        for (int k = 1; k < 64; ++k)   QSP_REC(rlane(hAx, k), rlane(hAy, k))
        #pragma unroll 4
        for (int k = 0; k < 64; ++k)   QSP_REC(rlane(hBx, k), rlane(hBy, k))
        #undef QSP_REC

        // gamma_{2L}, gamma_{2L+1} -> one 16B store (16B-aligned: 2L even)
        *(float4*)&gsh2[2 * lane] = make_float4(A0r, A0i, A1r, A1i);
    }

    // ---- per-thread prologue (all waves; overlaps gamma wave's chain) ------
    // seeds: c = cos th, s = sin th; prev = cos(-th), sin(-th); K = 2cos2th
    const float th8[8] = {ta.x, ta.y, ta.z, ta.w, tb.x, tb.y, tb.z, tb.w};
    float c0v[8], c1v[8], s0v[8], s1v[8], Kv[8], accr[8], acci[8];
    #pragma unroll
    for (int e = 0; e < 8; ++e) {
        float s, c;
        __sincosf(th8[e], &s, &c);
        c1v[e] = c;  s1v[e] = s;
        c0v[e] = c;  s0v[e] = -s;                 // k = -1 terms
        Kv[e]  = fmaf(-4.f * s, s, 2.f);          // 2 cos 2th = 2 - 4 sin^2
        accr[e] = 0.f; acci[e] = 0.f;
    }

    __syncthreads();

    // lane k derives its own (P_k, Q_k) from gamma (one-time, 2x ds_read_b64)
    const float2 ga = gsh2[63 - lane];            // gamma_{63-k}
    const float2 gb = gsh2[64 + lane];            // gamma_{64+k}
    const float Pr = ga.x + gb.x, Pi = ga.y + gb.y;
    const float Qr = ga.y - gb.y, Qi = gb.x - ga.x;

    // ---- harmonic sum, k = 0..63 (m = 2k+1); coeffs via readlane -----------
    #pragma unroll 2
    for (int k = 0; k < 64; ++k) {
        const float pr = rlane(Pr, k), pi = rlane(Pi, k);
        const float qr = rlane(Qr, k), qi = rlane(Qi, k);
        #pragma unroll
        for (int e = 0; e < 8; ++e) {
            accr[e] = fmaf(pr, c1v[e], fmaf(qr, s1v[e], accr[e]));
            acci[e] = fmaf(pi, c1v[e], fmaf(qi, s1v[e], acci[e]));
            const float cn = fmaf(Kv[e], c1v[e], -c0v[e]);
            const float sn = fmaf(Kv[e], s1v[e], -s0v[e]);
            c0v[e] = c1v[e]; c1v[e] = cn;
            s0v[e] = s1v[e]; s1v[e] = sn;
        }
    }

    if (idx < Bq8) {
        float4* o4 = (float4*)out;
        const int ib = 2 * Bq8;   // imag base in float4 units (= B/4)
        o4[2 * idx]          = make_float4(accr[0], accr[1], accr[2], accr[3]);
        o4[2 * idx + 1]      = make_float4(accr[4], accr[5], accr[6], accr[7]);
        o4[ib + 2 * idx]     = make_float4(acci[0], acci[1], acci[2], acci[3]);
        o4[ib + 2 * idx + 1] = make_float4(acci[4], acci[5], acci[6], acci[7]);
    }
}

extern "C" void kernel_launch(void* const* d_in, const int* in_sizes, int n_in,
                              void* d_out, int out_size, void* d_ws, size_t ws_size,
                              hipStream_t stream)
{
    const float* th   = (const float*)d_in[0];
    const float* phis = (const float*)d_in[1];
    float* out = (float*)d_out;
    const int B = in_sizes[0];          // 2097152
    const int Bq8 = B >> 3;             // 262144 threads
    const int block = 256;              // 4 waves
    const int grid = (Bq8 + block - 1) / block;   // 1024 blocks = 4/CU, 16 waves/CU
    qsp_fused<<<grid, block, 0, stream>>>(th, phis, out, Bq8);
}